// Round 11
// baseline (386.461 us; speedup 1.0000x reference)
//
#include <hip/hip_runtime.h>
#include <hip/hip_fp8.h>
#include <cstdint>

// ---------------------------------------------------------------------------
// GNN pipeline: corr-adjacency (bitmask) -> SAGEConv -> SAGPool -> SAGEConv ->
// SAGPool -> mean pool -> MLP head.
// R2-R10: see history.  R11: gemm gets an EXPLICIT double-buffered fragment
// pipeline (frag[2][..], prologue load, load k+1 before MFMA of k) — R10's
// VGPR=100 showed only one chunk's fragments were ever live, serializing
// load-burst -> vmcnt-drain -> MFMA-burst per wave at 2 waves/SIMD.
// C stores nontemporal (YR1 67MB > L2; keep L2 for A/B).
// ---------------------------------------------------------------------------

typedef __bf16 bf16x8 __attribute__((ext_vector_type(8)));
typedef float  floatx4 __attribute__((ext_vector_type(4)));

#define MFMA_BF16(a, b, c) __builtin_amdgcn_mfma_f32_16x16x32_bf16((a), (b), (c), 0, 0, 0)
#define MFMA_FP8(a, b, c)  __builtin_amdgcn_mfma_f32_16x16x32_fp8_fp8((a), (b), (c), 0, 0, 0)

static constexpr int BATCH = 64, NNODE = 1024, FIN = 195, FPAD = 224;
static constexpr int HD = 128, OD = 64, KP1 = 512, KP2 = 256;

// ---- workspace layout (bytes) ---------------------------------------------
static constexpr size_t OFF_GHI   = 0;          // x1g hi   [B*512*128] bf16
static constexpr size_t OFF_GLO   = 8388608;    // x1g lo
static constexpr size_t OFF_A1B   = 16777216;   // A1 bits  [B*512][8] u64
static constexpr size_t OFF_YR2   = 18874368;   // [B*512][128] f32
static constexpr size_t OFF_X2    = 35651584;   // [B*512][64]  f32
static constexpr size_t OFF_XHI   = 0;          // [B*N][224] bf16
static constexpr size_t OFF_XLO   = 29360128;
static constexpr size_t OFF_ABITS = 58720256;   // [B*N][64] u16 (= [B*N][16] u64)
static constexpr size_t OFF_X1    = 67108864;   // [B*N][128] f32
static constexpr size_t OFF_P1    = 100663296;
static constexpr size_t OFF_Q1    = OFF_P1 + 262144;
static constexpr size_t OFF_IDX1  = OFF_Q1 + 262144;
static constexpr size_t OFF_GATE1 = OFF_IDX1 + 131072;
static constexpr size_t OFF_P2    = OFF_GATE1 + 131072;
static constexpr size_t OFF_Q2    = OFF_P2 + 131072;
static constexpr size_t OFF_W1HI  = OFF_Q2 + 131072;     // [256][224] bf16
static constexpr size_t OFF_W1LO  = OFF_W1HI + 114688;
static constexpr size_t OFF_W2HI  = OFF_W1LO + 114688;   // [128][128] bf16
static constexpr size_t OFF_W2LO  = OFF_W2HI + 32768;
static constexpr size_t OFF_XHAT  = 102760448;  // [B*N][224] fp8 (dead after corr)
static constexpr size_t OFF_YR1   = 102760448 + 16777216;  // [B*N][256] f32

static __device__ __forceinline__ unsigned char to_fp8(float v) {
  __hip_fp8_e4m3 q(v);
  return *(unsigned char*)&q;
}

// ---------------------------------------------------------------------------
// K0: prep (per-row normalize + split-bf16 + fp8 xhat) fused with weight pack.
__global__ __launch_bounds__(256) void prep_pack_kernel(
    const float* __restrict__ x, __bf16* __restrict__ xhi,
    __bf16* __restrict__ xlo, unsigned char* __restrict__ xhat8,
    const float* __restrict__ W1l, const float* __restrict__ W1r,
    __bf16* __restrict__ hi1, __bf16* __restrict__ lo1,
    const float* __restrict__ W2l, const float* __restrict__ W2r,
    __bf16* __restrict__ hi2, __bf16* __restrict__ lo2) {
  int bid = blockIdx.x;
  if (bid < 16384) {
    int row  = bid * 4 + (threadIdx.x >> 6);
    int lane = threadIdx.x & 63;
    const float* xr = x + (long)row * FIN;
    int k0 = lane * 4;
    float v[4];
#pragma unroll
    for (int i = 0; i < 4; ++i) v[i] = (k0 + i < FIN) ? xr[k0 + i] : 0.f;
    float s = v[0] + v[1] + v[2] + v[3];
#pragma unroll
    for (int o = 32; o; o >>= 1) s += __shfl_xor(s, o);
    float mean = s * (1.f / (float)FIN);
    float c[4], ss = 0.f;
#pragma unroll
    for (int i = 0; i < 4; ++i) {
      c[i] = (k0 + i < FIN) ? (v[i] - mean) : 0.f;
      ss += c[i] * c[i];
    }
#pragma unroll
    for (int o = 32; o; o >>= 1) ss += __shfl_xor(ss, o);
    float inv = rsqrtf(fmaxf(ss, 1e-12f));
    if (k0 < FPAD) {
      __bf16 hi4[4], lo4[4];
      unsigned char h8[4];
#pragma unroll
      for (int i = 0; i < 4; ++i) {
        float xv = (k0 + i < FIN) ? v[i] : 0.f;
        __bf16 h = (__bf16)xv;
        hi4[i] = h;
        lo4[i] = (__bf16)(xv - (float)h);
        h8[i] = to_fp8(c[i] * inv);
      }
      long base = (long)row * FPAD + k0;
      *(uint2*)&xhi[base] = *(const uint2*)hi4;
      *(uint2*)&xlo[base] = *(const uint2*)lo4;
      *(unsigned int*)&xhat8[base] = *(const unsigned int*)h8;
    }
  } else if (bid < 16384 + 224) {
    int idx = (bid - 16384) * 256 + threadIdx.x;  // 256*224
    int h = idx / FPAD, k = idx % FPAD;
    float v = 0.f;
    if (k < FIN) v = (h < HD) ? W1l[h * FIN + k] : W1r[(h - HD) * FIN + k];
    __bf16 a = (__bf16)v;
    hi1[idx] = a;
    lo1[idx] = (__bf16)(v - (float)a);
  } else {
    int idx = (bid - 16384 - 224) * 256 + threadIdx.x;  // 128*128
    int h = idx / HD, k = idx % HD;
    float v = (h < OD) ? W2l[h * HD + k] : W2r[(h - OD) * HD + k];
    __bf16 a = (__bf16)v;
    hi2[idx] = a;
    lo2[idx] = (__bf16)(v - (float)a);
  }
}

// ---------------------------------------------------------------------------
// K1: corr bits, FP8.  Upper-triangular 128x128 blocks (36/batch), XCD swizzle.
static constexpr int CKB = 48;  // LDS row stride in BYTES for a 32-wide K chunk
__global__ __launch_bounds__(256) void corr_kernel(
    const unsigned char* __restrict__ xhat8, unsigned short* __restrict__ Abits) {
  __shared__ __align__(16) unsigned char sI[128 * CKB];
  __shared__ __align__(16) unsigned char sJ[128 * CKB];
  int bid = blockIdx.x;                 // 2304 = 8 xcd * 8 bh * 36 pair
  int xcd = bid & 7;
  int m = bid >> 3;
  int b = xcd + ((m & 7) << 3);
  int rem = m >> 3, bi = 0;             // triangular decode -> (bi <= bj)
  while (rem >= 8 - bi) { rem -= 8 - bi; ++bi; }
  int bj = bi + rem;
  int i0 = bi * 128, j0 = bj * 128;
  const unsigned char* Xb = xhat8 + (long)b * NNODE * FPAD;
  int lane = threadIdx.x & 63, wave = threadIdx.x >> 6;
  int wi = (wave >> 1) * 64, wj = (wave & 1) * 64;
  int lr = lane & 15, lk8 = (lane >> 4) * 8;  // byte offset of 8-elem fragment
  int strow = threadIdx.x & 127;
  int sbuf = threadIdx.x >> 7;          // 0 -> I, 1 -> J
  floatx4 zero = {0.f, 0.f, 0.f, 0.f};
  floatx4 acc[4][4];
#pragma unroll
  for (int i = 0; i < 4; ++i)
#pragma unroll
    for (int j = 0; j < 4; ++j) acc[i][j] = zero;
  for (int kk = 0; kk < 7; ++kk) {
    int k0 = kk * 32;
    __syncthreads();
    {
      unsigned char* dst = (sbuf ? sJ : sI) + strow * CKB;
      const unsigned char* src = Xb + (long)((sbuf ? j0 : i0) + strow) * FPAD + k0;
      *(uint4*)(dst)      = *(const uint4*)(src);
      *(uint4*)(dst + 16) = *(const uint4*)(src + 16);
    }
    __syncthreads();
    long long af[4], bf[4];
#pragma unroll
    for (int t = 0; t < 4; ++t) {
      af[t] = *(const long long*)&sI[(wi + t * 16 + lr) * CKB + lk8];
      bf[t] = *(const long long*)&sJ[(wj + t * 16 + lr) * CKB + lk8];
    }
#pragma unroll
    for (int ti = 0; ti < 4; ++ti)
#pragma unroll
      for (int tj = 0; tj < 4; ++tj)
        acc[ti][tj] = MFMA_FP8(af[ti], bf[tj], acc[ti][tj]);
  }
#pragma unroll
  for (int ti = 0; ti < 4; ++ti)
#pragma unroll
    for (int tj = 0; tj < 4; ++tj) {
      floatx4 a = acc[ti][tj];
      unsigned long long m0 = __ballot(a[0] > 0.5f);
      unsigned long long m1 = __ballot(a[1] > 0.5f);
      unsigned long long m2 = __ballot(a[2] > 0.5f);
      unsigned long long m3 = __ballot(a[3] > 0.5f);
      if (lane < 16) {
        unsigned long long mm = (lane & 2) ? ((lane & 1) ? m3 : m2)
                                           : ((lane & 1) ? m1 : m0);
        unsigned short piece = (unsigned short)(mm >> ((lane >> 2) * 16));
        int grow = i0 + wi + ti * 16 + lane;
        int gcol = (j0 + wj + tj * 16) >> 4;
        Abits[((long)b * NNODE + grow) * 64 + gcol] = piece;
      }
    }
}

// ---------------------------------------------------------------------------
// K2/K7: C = A @ B^T, 3-term split bf16, LDS-free, compile-time K,
// EXPLICIT double-buffered fragment pipeline (R11).  256 threads, 64x64/wave.
// Blocks past mblocks*NCOL run the lower-triangle bit-transpose fold.
template <int K, int NCOL>
__global__ __launch_bounds__(256, 2) void gemm_split_kernel(
    const __bf16* __restrict__ Ahi, const __bf16* __restrict__ Alo,
    const __bf16* __restrict__ Bhi, const __bf16* __restrict__ Blo,
    float* __restrict__ C, int mblocks,
    unsigned long long* __restrict__ A64, int ntrans) {
  constexpr int ldc = NCOL * 128;
  constexpr int NK = K >> 5;
  int bid = blockIdx.x;
  if (bid >= mblocks * NCOL) {
    int t = bid - mblocks * NCOL;
    if (t >= ntrans) return;
    int b = t / 28, pi = t % 28;
    int rem = pi, rb = 1;
    while (rem >= rb) { rem -= rb; ++rb; }
    int cb = rem;                    // rb > cb, 128-block coords
    int wave = threadIdx.x >> 6, lane = threadIdx.x & 63;
    int dr = rb * 2 + (wave >> 1);   // dest 64-tile row
    int dc = cb * 2 + (wave & 1);    // dest 64-tile col
    long base = (long)b * NNODE;
    unsigned long long xv = A64[(base + dc * 64 + lane) * 16 + dr];
    const unsigned long long M1  = 0x5555555555555555ULL;
    const unsigned long long M2  = 0x3333333333333333ULL;
    const unsigned long long M4  = 0x0F0F0F0F0F0F0F0FULL;
    const unsigned long long M8  = 0x00FF00FF00FF00FFULL;
    const unsigned long long M16 = 0x0000FFFF0000FFFFULL;
    const unsigned long long M32 = 0x00000000FFFFFFFFULL;
#define TSTEP(Kk, M)                                                      \
    {                                                                     \
      unsigned long long y = __shfl_xor(xv, Kk);                          \
      xv = ((lane & Kk) == 0) ? ((xv & (M)) | ((y & (M)) << Kk))          \
                              : ((xv & ~(M)) | ((y & ~(M)) >> Kk));       \
    }
    TSTEP(1, M1) TSTEP(2, M2) TSTEP(4, M4) TSTEP(8, M8) TSTEP(16, M16) TSTEP(32, M32)
#undef TSTEP
    A64[(base + dr * 64 + lane) * 16 + dc] = xv;
    return;
  }
  int mrow, col;
  if (NCOL == 2) {
    int xcd = bid & 7;               // pair (m, col0/1) shares bid mod 8
    int q = bid >> 3;
    col = q & 1;
    mrow = (xcd << 6) + (q >> 1);
  } else {
    mrow = bid;
    col = 0;
  }
  long row0 = (long)mrow * 128;
  int col0 = col * 128;
  int lane = threadIdx.x & 63, wave = threadIdx.x >> 6;
  int wi = (wave >> 1) * 64, wj = (wave & 1) * 64;
  int lr = lane & 15, lk = (lane >> 4) * 8;
  const __bf16* pAh = Ahi + (row0 + wi + lr) * (long)K + lk;
  const __bf16* pAl = Alo + (row0 + wi + lr) * (long)K + lk;
  const __bf16* pBh = Bhi + (long)(col0 + wj + lr) * K + lk;
  const __bf16* pBl = Blo + (long)(col0 + wj + lr) * K + lk;
  floatx4 zero = {0.f, 0.f, 0.f, 0.f};
  floatx4 acc[4][4];
#pragma unroll
  for (int i = 0; i < 4; ++i)
#pragma unroll
    for (int j = 0; j < 4; ++j) acc[i][j] = zero;
  bf16x8 ah[2][4], al[2][4], bh[2][4], bl[2][4];
#pragma unroll
  for (int t = 0; t < 4; ++t) {
    ah[0][t] = *(const bf16x8*)(pAh + (long)t * 16 * K);
    al[0][t] = *(const bf16x8*)(pAl + (long)t * 16 * K);
    bh[0][t] = *(const bf16x8*)(pBh + (long)t * 16 * K);
    bl[0][t] = *(const bf16x8*)(pBl + (long)t * 16 * K);
  }
#pragma unroll
  for (int kk = 0; kk < NK; ++kk) {
    int cur = kk & 1, nxt = cur ^ 1;
    if (kk + 1 < NK) {
      int k0 = (kk + 1) * 32;
#pragma unroll
      for (int t = 0; t < 4; ++t) {
        ah[nxt][t] = *(const bf16x8*)(pAh + (long)t * 16 * K + k0);
        al[nxt][t] = *(const bf16x8*)(pAl + (long)t * 16 * K + k0);
        bh[nxt][t] = *(const bf16x8*)(pBh + (long)t * 16 * K + k0);
        bl[nxt][t] = *(const bf16x8*)(pBl + (long)t * 16 * K + k0);
      }
    }
#pragma unroll
    for (int tj = 0; tj < 4; ++tj)
#pragma unroll
      for (int ti = 0; ti < 4; ++ti) {
        acc[ti][tj] = MFMA_BF16(ah[cur][ti], bh[cur][tj], acc[ti][tj]);
        acc[ti][tj] = MFMA_BF16(ah[cur][ti], bl[cur][tj], acc[ti][tj]);
        acc[ti][tj] = MFMA_BF16(al[cur][ti], bh[cur][tj], acc[ti][tj]);
      }
  }
#pragma unroll
  for (int ti = 0; ti < 4; ++ti)
#pragma unroll
    for (int tj = 0; tj < 4; ++tj)
#pragma unroll
      for (int rr = 0; rr < 4; ++rr) {
        long grow = row0 + wi + ti * 16 + (lane >> 4) * 4 + rr;
        int gcol = col0 + wj + tj * 16 + (lane & 15);
        __builtin_nontemporal_store(acc[ti][tj][rr], &C[grow * ldc + gcol]);
      }
}

// ---------------------------------------------------------------------------
// K3: sage1 scan-once-then-gather.
__global__ __launch_bounds__(256) void sage1_kernel(
    const unsigned int* __restrict__ Abits32, const float* __restrict__ YR1,
    const float* __restrict__ b1l, const float* __restrict__ Wrel,
    const float* __restrict__ Wroot, float* __restrict__ x1,
    float* __restrict__ p1, float* __restrict__ q1) {
  int half = threadIdx.x >> 7;
  int node = blockIdx.x * 2 + half;  // b*1024+n
  int b = node >> 10;
  int h = threadIdx.x & 127;
  __shared__ int list[2][1024];
  __shared__ int s_deg[2];
  __shared__ float redp[2][2], redq[2][2];
  if (h < 32) {
    unsigned int word = Abits32[(long)node * 32 + h];
    int cnt = __popc(word);
    int off = cnt;
#pragma unroll
    for (int o = 1; o < 32; o <<= 1) {
      int v = __shfl_up(off, o);
      if (h >= o) off += v;
    }
    off -= cnt;  // exclusive prefix (ascending word order -> ordered list)
    if (h == 31) s_deg[half] = off + cnt;
    int basei = h * 32;
    while (word) {
      int t = __ffs(word) - 1;
      word &= word - 1;
      list[half][off++] = basei + t;
    }
  }
  __syncthreads();
  int deg = s_deg[half];
  long ybase = (long)(b << 10) * 256;
  float accv = 0.f;
  for (int d = 0; d < deg; ++d)
    accv += YR1[ybase + (long)list[half][d] * 256 + h];
  float R = YR1[(long)node * 256 + 128 + h];
  float v = accv / (float)(deg < 1 ? 1 : deg) + b1l[h] + R;
  v = fmaxf(v, 0.f);
  x1[(long)node * 128 + h] = v;
  float pv = v * Wrel[h], qv = v * Wroot[h];
#pragma unroll
  for (int o = 32; o; o >>= 1) { pv += __shfl_xor(pv, o); qv += __shfl_xor(qv, o); }
  int wv = h >> 6, lane = h & 63;
  if (lane == 0) { redp[half][wv] = pv; redq[half][wv] = qv; }
  __syncthreads();
  if (h == 0) {
    p1[node] = redp[half][0] + redp[half][1];
    q1[node] = redq[half][0] + redq[half][1];
  }
}

// ---------------------------------------------------------------------------
// K4+K5 fused: per-batch score (thread-per-row) + radix top-k selection.
__global__ void scoretopk_kernel(const unsigned int* __restrict__ bits32,
                                 const float* __restrict__ p,
                                 const float* __restrict__ q,
                                 const float* __restrict__ brel,
                                 int* __restrict__ idx_out,
                                 float* __restrict__ gate_out,
                                 int nwords, int rpb_shift, int k) {
  int b = blockIdx.x, tid = threadIdx.x;
  int row = (b << rpb_shift) + tid;
  const unsigned int* wptr = bits32 + (long)row * nwords;
  const float* pb = p + ((long)b << rpb_shift);
  float s = q[row] + brel[0];
  for (int w = 0; w < nwords; ++w) {
    unsigned int word = wptr[w];
    while (word) {
      int t = __ffs(word) - 1;
      word &= word - 1;
      s += pb[w * 32 + t];
    }
  }
  unsigned int fb = __float_as_uint(s);
  unsigned int key = (fb & 0x80000000u) ? ~fb : (fb | 0x80000000u);
  __shared__ int hist[256];
  __shared__ unsigned int sh_prefix;
  __shared__ int sh_target, cnt_gt, cnt_eq, outpos;
  if (tid == 0) { sh_prefix = 0; sh_target = k; cnt_gt = 0; cnt_eq = 0; outpos = 0; }
  for (int shift = 24; shift >= 0; shift -= 8) {
    if (tid < 256) hist[tid] = 0;
    __syncthreads();
    unsigned int prefix = sh_prefix;
    bool inset = (shift == 24) || ((key >> (shift + 8)) == (prefix >> (shift + 8)));
    if (inset) atomicAdd(&hist[(key >> shift) & 255], 1);
    __syncthreads();
    if (tid < 64) {
      int lane = tid;
      int bb0 = hist[255 - 4 * lane];
      int bb1 = hist[254 - 4 * lane];
      int bb2 = hist[253 - 4 * lane];
      int bb3 = hist[252 - 4 * lane];
      int c0 = bb0, c1 = c0 + bb1, c2 = c1 + bb2, c3 = c2 + bb3;
      int incl = c3;
#pragma unroll
      for (int o = 1; o < 64; o <<= 1) {
        int v = __shfl_up(incl, o);
        if (lane >= o) incl += v;
      }
      int excl = incl - c3;
      int target = sh_target;  // read before any lane writes (lockstep)
      int cum[4] = {excl + c0, excl + c1, excl + c2, excl + c3};
      int prev = excl;
#pragma unroll
      for (int i = 0; i < 4; ++i) {
        if (cum[i] >= target && prev < target) {
          int bin = 255 - (4 * lane + i);
          sh_prefix = prefix | ((unsigned int)bin << shift);
          sh_target = target - prev;
        }
        prev = cum[i];
      }
    }
    __syncthreads();
  }
  unsigned int T = sh_prefix;
  if (key > T) atomicAdd(&cnt_gt, 1);
  __syncthreads();
  int E = k - cnt_gt;
  bool sel = (key > T);
  if (!sel && key == T) sel = (atomicAdd(&cnt_eq, 1) < E);
  if (sel) {
    int posn = atomicAdd(&outpos, 1);
    idx_out[b * k + posn] = tid;
    gate_out[b * k + posn] = tanhf(s);
  }
}

// K6: fused gather: x1 rows * tanh gate -> split bf16, and A1 bit gather.
__global__ __launch_bounds__(256) void gather_kernel(
    const float* __restrict__ x1, const int* __restrict__ idx,
    const float* __restrict__ gate, __bf16* __restrict__ ghi,
    __bf16* __restrict__ glo, const unsigned int* __restrict__ Abits32,
    unsigned long long* __restrict__ A1bits) {
  int bid = blockIdx.x;
  if (bid < 16384) {
    long e = (long)bid * 256 + threadIdx.x;  // B*512*128
    int h = (int)(e & 127);
    int i = (int)((e >> 7) & 511);
    int b = (int)(e >> 16);
    int srow = idx[(b << 9) + i];
    float v = x1[((long)(b << 10) + srow) * 128 + h] * gate[(b << 9) + i];
    __bf16 a = (__bf16)v;
    ghi[e] = a;
    glo[e] = (__bf16)(v - (float)a);
  } else {
    int gi = (bid - 16384) * 4 + (threadIdx.x >> 6);  // b*512+i
    int lane = threadIdx.x & 63;
    int b = gi >> 9;
    int srow = idx[gi];
    const unsigned int* src = Abits32 + ((long)(b << 10) + srow) * 32;
    const int* idxb = idx + (b << 9);
#pragma unroll
    for (int t = 0; t < 8; ++t) {
      int cj = idxb[t * 64 + lane];
      int bit = (src[cj >> 5] >> (cj & 31)) & 1;
      unsigned long long m = __ballot(bit);
      if (lane == 0) A1bits[(long)gi * 8 + t] = m;
    }
  }
}

// K8: sage2 scan-once-then-gather — 4 nodes per 256-thread block.
__global__ __launch_bounds__(256) void sage2_kernel(
    const unsigned int* __restrict__ A1b32, const float* __restrict__ YR2,
    const float* __restrict__ b2l, const float* __restrict__ Wrel,
    const float* __restrict__ Wroot, float* __restrict__ x2,
    float* __restrict__ p2, float* __restrict__ q2) {
  int qw = threadIdx.x >> 6;
  int row = blockIdx.x * 4 + qw;  // b*512+i
  int b = row >> 9;
  int h = threadIdx.x & 63;
  __shared__ int list[4][512];
  __shared__ int s_deg[4];
  if (h < 16) {
    unsigned int word = A1b32[(long)row * 16 + h];
    int cnt = __popc(word);
    int off = cnt;
#pragma unroll
    for (int o = 1; o < 16; o <<= 1) {
      int v = __shfl_up(off, o);
      if (h >= o) off += v;
    }
    off -= cnt;
    if (h == 15) s_deg[qw] = off + cnt;
    int basei = h * 32;
    while (word) {
      int t = __ffs(word) - 1;
      word &= word - 1;
      list[qw][off++] = basei + t;
    }
  }
  __syncthreads();
  int deg = s_deg[qw];
  long ybase = (long)(b << 9) * 128;
  float accv = 0.f;
  for (int d = 0; d < deg; ++d)
    accv += YR2[ybase + (long)list[qw][d] * 128 + h];
  float R = YR2[(long)row * 128 + 64 + h];
  float v = fmaxf(accv / (float)(deg < 1 ? 1 : deg) + b2l[h] + R, 0.f);
  x2[(long)row * 64 + h] = v;
  float pv = v * Wrel[h], qv = v * Wroot[h];
#pragma unroll
  for (int o = 32; o; o >>= 1) { pv += __shfl_xor(pv, o); qv += __shfl_xor(qv, o); }
  if (h == 0) { p2[row] = pv; q2[row] = qv; }
}

// ---------------------------------------------------------------------------
// K9+K10+K11 fused: per-batch score2 + topk2 (idx/gate in LDS) + MLP head.
__global__ __launch_bounds__(512) void scoretopk_head_kernel(
    const unsigned int* __restrict__ A1b32, const float* __restrict__ p2,
    const float* __restrict__ q2, const float* __restrict__ brel,
    const float* __restrict__ x2, const float* __restrict__ fc1_w,
    const float* __restrict__ fc1_b, const float* __restrict__ g1,
    const float* __restrict__ bb1, const float* __restrict__ m1,
    const float* __restrict__ v1, const float* __restrict__ fc2_w,
    const float* __restrict__ fc2_b, const float* __restrict__ g2,
    const float* __restrict__ bb2, const float* __restrict__ m2,
    const float* __restrict__ v2, const float* __restrict__ fc3_w,
    const float* __restrict__ fc3_b, float* __restrict__ out) {
  int b = blockIdx.x, tid = threadIdx.x;
  // ---- score (thread-per-row, 512 rows, 16 words) ----
  int row = (b << 9) + tid;
  const unsigned int* wptr = A1b32 + (long)row * 16;
  const float* pb = p2 + ((long)b << 9);
  float s = q2[row] + brel[0];
  for (int w = 0; w < 16; ++w) {
    unsigned int word = wptr[w];
    while (word) {
      int t = __ffs(word) - 1;
      word &= word - 1;
      s += pb[w * 32 + t];
    }
  }
  // ---- top-256 radix select into LDS ----
  constexpr int k = KP2;
  unsigned int fb = __float_as_uint(s);
  unsigned int key = (fb & 0x80000000u) ? ~fb : (fb | 0x80000000u);
  __shared__ int hist[256];
  __shared__ int idx2s[256];
  __shared__ float gate2s[256];
  __shared__ unsigned int sh_prefix;
  __shared__ int sh_target, cnt_gt, cnt_eq, outpos;
  if (tid == 0) { sh_prefix = 0; sh_target = k; cnt_gt = 0; cnt_eq = 0; outpos = 0; }
  for (int shift = 24; shift >= 0; shift -= 8) {
    if (tid < 256) hist[tid] = 0;
    __syncthreads();
    unsigned int prefix = sh_prefix;
    bool inset = (shift == 24) || ((key >> (shift + 8)) == (prefix >> (shift + 8)));
    if (inset) atomicAdd(&hist[(key >> shift) & 255], 1);
    __syncthreads();
    if (tid < 64) {
      int lane = tid;
      int bb0 = hist[255 - 4 * lane];
      int bb1 = hist[254 - 4 * lane];
      int bb2 = hist[253 - 4 * lane];
      int bb3 = hist[252 - 4 * lane];
      int c0 = bb0, c1 = c0 + bb1, c2 = c1 + bb2, c3 = c2 + bb3;
      int incl = c3;
#pragma unroll
      for (int o = 1; o < 64; o <<= 1) {
        int v = __shfl_up(incl, o);
        if (lane >= o) incl += v;
      }
      int excl = incl - c3;
      int target = sh_target;
      int cum[4] = {excl + c0, excl + c1, excl + c2, excl + c3};
      int prev = excl;
#pragma unroll
      for (int i = 0; i < 4; ++i) {
        if (cum[i] >= target && prev < target) {
          int bin = 255 - (4 * lane + i);
          sh_prefix = prefix | ((unsigned int)bin << shift);
          sh_target = target - prev;
        }
        prev = cum[i];
      }
    }
    __syncthreads();
  }
  unsigned int T = sh_prefix;
  if (key > T) atomicAdd(&cnt_gt, 1);
  __syncthreads();
  int E = k - cnt_gt;
  bool sel = (key > T);
  if (!sel && key == T) sel = (atomicAdd(&cnt_eq, 1) < E);
  if (sel) {
    int posn = atomicAdd(&outpos, 1);
    idx2s[posn] = tid;
    gate2s[posn] = tanhf(s);
  }
  __syncthreads();
  // ---- head: mean pool over selected + MLP + softmax ----
  __shared__ float part[8][64];
  __shared__ float pooled[64];
  __shared__ float h1[512];
  __shared__ float h2[256];
  __shared__ float zz[2];
  int h = tid & 63, grp = tid >> 6;
  float sp = 0.f;
  for (int i = grp * 32; i < grp * 32 + 32; ++i) {
    int si = idx2s[i];
    sp += x2[((long)(b << 9) + si) * 64 + h] * gate2s[i];
  }
  part[grp][h] = sp;
  __syncthreads();
  if (tid < 64) {
    float t = 0.f;
#pragma unroll
    for (int g = 0; g < 8; ++g) t += part[g][tid];
    pooled[tid] = t * (1.f / 256.f);
  }
  __syncthreads();
  {
    float z = fc1_b[tid];
    for (int j = 0; j < 64; ++j) z += pooled[j] * fc1_w[tid * 64 + j];
    z = fmaxf(z, 0.f);
    h1[tid] = g1[tid] * (z - m1[tid]) * rsqrtf(v1[tid] + 1e-5f) + bb1[tid];
  }
  __syncthreads();
  if (tid < 256) {
    float z = fc2_b[tid];
    for (int j = 0; j < 512; ++j) z += h1[j] * fc2_w[tid * 512 + j];
    z = fmaxf(z, 0.f);
    h2[tid] = g2[tid] * (z - m2[tid]) * rsqrtf(v2[tid] + 1e-5f) + bb2[tid];
  }
  __syncthreads();
  if (tid < 2) {
    float z = fc3_b[tid];
    for (int j = 0; j < 256; ++j) z += h2[j] * fc3_w[tid * 256 + j];
    zz[tid] = z;
  }
  __syncthreads();
  if (tid == 0) {
    float mx = fmaxf(zz[0], zz[1]);
    float e0 = expf(zz[0] - mx), e1 = expf(zz[1] - mx);
    float inv = 1.f / (e0 + e1);
    out[b * 2 + 0] = e0 * inv;
    out[b * 2 + 1] = e1 * inv;
  }
}

// ---------------------------------------------------------------------------
extern "C" void kernel_launch(void* const* d_in, const int* in_sizes, int n_in,
                              void* d_out, int out_size, void* d_ws, size_t ws_size,
                              hipStream_t stream) {
  (void)in_sizes; (void)n_in; (void)out_size; (void)ws_size;
  const float* input   = (const float*)d_in[0];
  const float* W1l     = (const float*)d_in[1];
  const float* b1l     = (const float*)d_in[2];
  const float* W1r     = (const float*)d_in[3];
  const float* Wp1_rel = (const float*)d_in[4];
  const float* bp1_rel = (const float*)d_in[5];
  const float* Wp1_root= (const float*)d_in[6];
  const float* W2l     = (const float*)d_in[7];
  const float* b2l     = (const float*)d_in[8];
  const float* W2r     = (const float*)d_in[9];
  const float* Wp2_rel = (const float*)d_in[10];
  const float* bp2_rel = (const float*)d_in[11];
  const float* Wp2_root= (const float*)d_in[12];
  const float* fc1_w   = (const float*)d_in[13];
  const float* fc1_b   = (const float*)d_in[14];
  const float* bn1_g   = (const float*)d_in[15];
  const float* bn1_b   = (const float*)d_in[16];
  const float* bn1_m   = (const float*)d_in[17];
  const float* bn1_v   = (const float*)d_in[18];
  const float* fc2_w   = (const float*)d_in[19];
  const float* fc2_b   = (const float*)d_in[20];
  const float* bn2_g   = (const float*)d_in[21];
  const float* bn2_b   = (const float*)d_in[22];
  const float* bn2_m   = (const float*)d_in[23];
  const float* bn2_v   = (const float*)d_in[24];
  const float* fc3_w   = (const float*)d_in[25];
  const float* fc3_b   = (const float*)d_in[26];

  char* ws = (char*)d_ws;
  __bf16* xhi   = (__bf16*)(ws + OFF_XHI);
  __bf16* xlo   = (__bf16*)(ws + OFF_XLO);
  unsigned char* xhat8 = (unsigned char*)(ws + OFF_XHAT);
  unsigned short* Abits = (unsigned short*)(ws + OFF_ABITS);
  const unsigned int* Abits32 = (const unsigned int*)(ws + OFF_ABITS);
  unsigned long long* A64 = (unsigned long long*)(ws + OFF_ABITS);
  float* YR1    = (float*)(ws + OFF_YR1);
  float* x1     = (float*)(ws + OFF_X1);
  float* p1     = (float*)(ws + OFF_P1);
  float* q1     = (float*)(ws + OFF_Q1);
  int*   idx1   = (int*)(ws + OFF_IDX1);
  float* gate1  = (float*)(ws + OFF_GATE1);
  float* p2     = (float*)(ws + OFF_P2);
  float* q2     = (float*)(ws + OFF_Q2);
  __bf16* w1hi  = (__bf16*)(ws + OFF_W1HI);
  __bf16* w1lo  = (__bf16*)(ws + OFF_W1LO);
  __bf16* w2hi  = (__bf16*)(ws + OFF_W2HI);
  __bf16* w2lo  = (__bf16*)(ws + OFF_W2LO);
  __bf16* ghi   = (__bf16*)(ws + OFF_GHI);
  __bf16* glo   = (__bf16*)(ws + OFF_GLO);
  unsigned long long* A1bits = (unsigned long long*)(ws + OFF_A1B);
  const unsigned int* A1b32  = (const unsigned int*)(ws + OFF_A1B);
  float* YR2    = (float*)(ws + OFF_YR2);
  float* x2     = (float*)(ws + OFF_X2);
  float* out    = (float*)d_out;

  prep_pack_kernel<<<16672, 256, 0, stream>>>(input, xhi, xlo, xhat8,
                                              W1l, W1r, w1hi, w1lo,
                                              W2l, W2r, w2hi, w2lo);
  corr_kernel<<<2304, 256, 0, stream>>>(xhat8, Abits);
  // gemm1: 512 M-blocks x 2 N-blocks (XCD-paired) + 1792 transpose blocks
  gemm_split_kernel<224, 2><<<1024 + 1792, 256, 0, stream>>>(
      xhi, xlo, w1hi, w1lo, YR1, 512, A64, 1792);
  sage1_kernel<<<32768, 256, 0, stream>>>(Abits32, YR1, b1l, Wp1_rel, Wp1_root, x1, p1, q1);
  scoretopk_kernel<<<64, 1024, 0, stream>>>(Abits32, p1, q1, bp1_rel, idx1, gate1,
                                            32, 10, KP1);
  gather_kernel<<<24576, 256, 0, stream>>>(x1, idx1, gate1, ghi, glo, Abits32, A1bits);
  gemm_split_kernel<128, 1><<<256, 256, 0, stream>>>(
      ghi, glo, w2hi, w2lo, YR2, 256, nullptr, 0);
  sage2_kernel<<<8192, 256, 0, stream>>>(A1b32, YR2, b2l, Wp2_rel, Wp2_root, x2, p2, q2);
  scoretopk_head_kernel<<<64, 512, 0, stream>>>(A1b32, p2, q2, bp2_rel, x2,
                                                fc1_w, fc1_b, bn1_g, bn1_b, bn1_m, bn1_v,
                                                fc2_w, fc2_b, bn2_g, bn2_b, bn2_m, bn2_v,
                                                fc3_w, fc3_b, out);
}

// Round 12
// 350.716 us; speedup vs baseline: 1.1019x; 1.1019x over previous
//
#include <hip/hip_runtime.h>
#include <hip/hip_fp8.h>
#include <cstdint>

// ---------------------------------------------------------------------------
// GNN pipeline: corr-adjacency (bitmask) -> SAGEConv -> SAGPool -> SAGEConv ->
// SAGPool -> mean pool -> MLP head.
// R2-R10: see history.  R11 (explicit gemm dbuf + nontemporal C) FAILED:
// VGPR=80 (compiler rematerialized), WRITE_SIZE +20MB -> reverted; gemm1's
// 52us is declared this structure's plateau.  R12: sage1/sage2 vectorized
// float4-per-lane (R11 profile showed sage1 54.9us all along — VALU-overhead
// bound at 8.4M scalar threads; 32 lanes/node x float4 cuts instr ~3x).
// ---------------------------------------------------------------------------

typedef __bf16 bf16x8 __attribute__((ext_vector_type(8)));
typedef float  floatx4 __attribute__((ext_vector_type(4)));

#define MFMA_BF16(a, b, c) __builtin_amdgcn_mfma_f32_16x16x32_bf16((a), (b), (c), 0, 0, 0)
#define MFMA_FP8(a, b, c)  __builtin_amdgcn_mfma_f32_16x16x32_fp8_fp8((a), (b), (c), 0, 0, 0)

static constexpr int BATCH = 64, NNODE = 1024, FIN = 195, FPAD = 224;
static constexpr int HD = 128, OD = 64, KP1 = 512, KP2 = 256;

// ---- workspace layout (bytes) ---------------------------------------------
static constexpr size_t OFF_GHI   = 0;          // x1g hi   [B*512*128] bf16
static constexpr size_t OFF_GLO   = 8388608;    // x1g lo
static constexpr size_t OFF_A1B   = 16777216;   // A1 bits  [B*512][8] u64
static constexpr size_t OFF_YR2   = 18874368;   // [B*512][128] f32
static constexpr size_t OFF_X2    = 35651584;   // [B*512][64]  f32
static constexpr size_t OFF_XHI   = 0;          // [B*N][224] bf16
static constexpr size_t OFF_XLO   = 29360128;
static constexpr size_t OFF_ABITS = 58720256;   // [B*N][64] u16 (= [B*N][16] u64)
static constexpr size_t OFF_X1    = 67108864;   // [B*N][128] f32
static constexpr size_t OFF_P1    = 100663296;
static constexpr size_t OFF_Q1    = OFF_P1 + 262144;
static constexpr size_t OFF_IDX1  = OFF_Q1 + 262144;
static constexpr size_t OFF_GATE1 = OFF_IDX1 + 131072;
static constexpr size_t OFF_P2    = OFF_GATE1 + 131072;
static constexpr size_t OFF_Q2    = OFF_P2 + 131072;
static constexpr size_t OFF_W1HI  = OFF_Q2 + 131072;     // [256][224] bf16
static constexpr size_t OFF_W1LO  = OFF_W1HI + 114688;
static constexpr size_t OFF_W2HI  = OFF_W1LO + 114688;   // [128][128] bf16
static constexpr size_t OFF_W2LO  = OFF_W2HI + 32768;
static constexpr size_t OFF_XHAT  = 102760448;  // [B*N][224] fp8 (dead after corr)
static constexpr size_t OFF_YR1   = 102760448 + 16777216;  // [B*N][256] f32

static __device__ __forceinline__ unsigned char to_fp8(float v) {
  __hip_fp8_e4m3 q(v);
  return *(unsigned char*)&q;
}

// ---------------------------------------------------------------------------
// K0: prep (per-row normalize + split-bf16 + fp8 xhat) fused with weight pack.
__global__ __launch_bounds__(256) void prep_pack_kernel(
    const float* __restrict__ x, __bf16* __restrict__ xhi,
    __bf16* __restrict__ xlo, unsigned char* __restrict__ xhat8,
    const float* __restrict__ W1l, const float* __restrict__ W1r,
    __bf16* __restrict__ hi1, __bf16* __restrict__ lo1,
    const float* __restrict__ W2l, const float* __restrict__ W2r,
    __bf16* __restrict__ hi2, __bf16* __restrict__ lo2) {
  int bid = blockIdx.x;
  if (bid < 16384) {
    int row  = bid * 4 + (threadIdx.x >> 6);
    int lane = threadIdx.x & 63;
    const float* xr = x + (long)row * FIN;
    int k0 = lane * 4;
    float v[4];
#pragma unroll
    for (int i = 0; i < 4; ++i) v[i] = (k0 + i < FIN) ? xr[k0 + i] : 0.f;
    float s = v[0] + v[1] + v[2] + v[3];
#pragma unroll
    for (int o = 32; o; o >>= 1) s += __shfl_xor(s, o);
    float mean = s * (1.f / (float)FIN);
    float c[4], ss = 0.f;
#pragma unroll
    for (int i = 0; i < 4; ++i) {
      c[i] = (k0 + i < FIN) ? (v[i] - mean) : 0.f;
      ss += c[i] * c[i];
    }
#pragma unroll
    for (int o = 32; o; o >>= 1) ss += __shfl_xor(ss, o);
    float inv = rsqrtf(fmaxf(ss, 1e-12f));
    if (k0 < FPAD) {
      __bf16 hi4[4], lo4[4];
      unsigned char h8[4];
#pragma unroll
      for (int i = 0; i < 4; ++i) {
        float xv = (k0 + i < FIN) ? v[i] : 0.f;
        __bf16 h = (__bf16)xv;
        hi4[i] = h;
        lo4[i] = (__bf16)(xv - (float)h);
        h8[i] = to_fp8(c[i] * inv);
      }
      long base = (long)row * FPAD + k0;
      *(uint2*)&xhi[base] = *(const uint2*)hi4;
      *(uint2*)&xlo[base] = *(const uint2*)lo4;
      *(unsigned int*)&xhat8[base] = *(const unsigned int*)h8;
    }
  } else if (bid < 16384 + 224) {
    int idx = (bid - 16384) * 256 + threadIdx.x;  // 256*224
    int h = idx / FPAD, k = idx % FPAD;
    float v = 0.f;
    if (k < FIN) v = (h < HD) ? W1l[h * FIN + k] : W1r[(h - HD) * FIN + k];
    __bf16 a = (__bf16)v;
    hi1[idx] = a;
    lo1[idx] = (__bf16)(v - (float)a);
  } else {
    int idx = (bid - 16384 - 224) * 256 + threadIdx.x;  // 128*128
    int h = idx / HD, k = idx % HD;
    float v = (h < OD) ? W2l[h * HD + k] : W2r[(h - OD) * HD + k];
    __bf16 a = (__bf16)v;
    hi2[idx] = a;
    lo2[idx] = (__bf16)(v - (float)a);
  }
}

// ---------------------------------------------------------------------------
// K1: corr bits, FP8.  Upper-triangular 128x128 blocks (36/batch), XCD swizzle.
static constexpr int CKB = 48;  // LDS row stride in BYTES for a 32-wide K chunk
__global__ __launch_bounds__(256) void corr_kernel(
    const unsigned char* __restrict__ xhat8, unsigned short* __restrict__ Abits) {
  __shared__ __align__(16) unsigned char sI[128 * CKB];
  __shared__ __align__(16) unsigned char sJ[128 * CKB];
  int bid = blockIdx.x;                 // 2304 = 8 xcd * 8 bh * 36 pair
  int xcd = bid & 7;
  int m = bid >> 3;
  int b = xcd + ((m & 7) << 3);
  int rem = m >> 3, bi = 0;             // triangular decode -> (bi <= bj)
  while (rem >= 8 - bi) { rem -= 8 - bi; ++bi; }
  int bj = bi + rem;
  int i0 = bi * 128, j0 = bj * 128;
  const unsigned char* Xb = xhat8 + (long)b * NNODE * FPAD;
  int lane = threadIdx.x & 63, wave = threadIdx.x >> 6;
  int wi = (wave >> 1) * 64, wj = (wave & 1) * 64;
  int lr = lane & 15, lk8 = (lane >> 4) * 8;  // byte offset of 8-elem fragment
  int strow = threadIdx.x & 127;
  int sbuf = threadIdx.x >> 7;          // 0 -> I, 1 -> J
  floatx4 zero = {0.f, 0.f, 0.f, 0.f};
  floatx4 acc[4][4];
#pragma unroll
  for (int i = 0; i < 4; ++i)
#pragma unroll
    for (int j = 0; j < 4; ++j) acc[i][j] = zero;
  for (int kk = 0; kk < 7; ++kk) {
    int k0 = kk * 32;
    __syncthreads();
    {
      unsigned char* dst = (sbuf ? sJ : sI) + strow * CKB;
      const unsigned char* src = Xb + (long)((sbuf ? j0 : i0) + strow) * FPAD + k0;
      *(uint4*)(dst)      = *(const uint4*)(src);
      *(uint4*)(dst + 16) = *(const uint4*)(src + 16);
    }
    __syncthreads();
    long long af[4], bf[4];
#pragma unroll
    for (int t = 0; t < 4; ++t) {
      af[t] = *(const long long*)&sI[(wi + t * 16 + lr) * CKB + lk8];
      bf[t] = *(const long long*)&sJ[(wj + t * 16 + lr) * CKB + lk8];
    }
#pragma unroll
    for (int ti = 0; ti < 4; ++ti)
#pragma unroll
      for (int tj = 0; tj < 4; ++tj)
        acc[ti][tj] = MFMA_FP8(af[ti], bf[tj], acc[ti][tj]);
  }
#pragma unroll
  for (int ti = 0; ti < 4; ++ti)
#pragma unroll
    for (int tj = 0; tj < 4; ++tj) {
      floatx4 a = acc[ti][tj];
      unsigned long long m0 = __ballot(a[0] > 0.5f);
      unsigned long long m1 = __ballot(a[1] > 0.5f);
      unsigned long long m2 = __ballot(a[2] > 0.5f);
      unsigned long long m3 = __ballot(a[3] > 0.5f);
      if (lane < 16) {
        unsigned long long mm = (lane & 2) ? ((lane & 1) ? m3 : m2)
                                           : ((lane & 1) ? m1 : m0);
        unsigned short piece = (unsigned short)(mm >> ((lane >> 2) * 16));
        int grow = i0 + wi + ti * 16 + lane;
        int gcol = (j0 + wj + tj * 16) >> 4;
        Abits[((long)b * NNODE + grow) * 64 + gcol] = piece;
      }
    }
}

// ---------------------------------------------------------------------------
// K2/K7: C = A @ B^T, 3-term split bf16, LDS-free, compile-time K
// (R10-measured-best: 256 threads, 64x64/wave, plain unroll, plain stores).
// Blocks past mblocks*NCOL run the lower-triangle bit-transpose fold.
template <int K, int NCOL>
__global__ __launch_bounds__(256, 2) void gemm_split_kernel(
    const __bf16* __restrict__ Ahi, const __bf16* __restrict__ Alo,
    const __bf16* __restrict__ Bhi, const __bf16* __restrict__ Blo,
    float* __restrict__ C, int mblocks,
    unsigned long long* __restrict__ A64, int ntrans) {
  constexpr int ldc = NCOL * 128;
  int bid = blockIdx.x;
  if (bid >= mblocks * NCOL) {
    int t = bid - mblocks * NCOL;
    if (t >= ntrans) return;
    int b = t / 28, pi = t % 28;
    int rem = pi, rb = 1;
    while (rem >= rb) { rem -= rb; ++rb; }
    int cb = rem;                    // rb > cb, 128-block coords
    int wave = threadIdx.x >> 6, lane = threadIdx.x & 63;
    int dr = rb * 2 + (wave >> 1);   // dest 64-tile row
    int dc = cb * 2 + (wave & 1);    // dest 64-tile col
    long base = (long)b * NNODE;
    unsigned long long xv = A64[(base + dc * 64 + lane) * 16 + dr];
    const unsigned long long M1  = 0x5555555555555555ULL;
    const unsigned long long M2  = 0x3333333333333333ULL;
    const unsigned long long M4  = 0x0F0F0F0F0F0F0F0FULL;
    const unsigned long long M8  = 0x00FF00FF00FF00FFULL;
    const unsigned long long M16 = 0x0000FFFF0000FFFFULL;
    const unsigned long long M32 = 0x00000000FFFFFFFFULL;
#define TSTEP(Kk, M)                                                      \
    {                                                                     \
      unsigned long long y = __shfl_xor(xv, Kk);                          \
      xv = ((lane & Kk) == 0) ? ((xv & (M)) | ((y & (M)) << Kk))          \
                              : ((xv & ~(M)) | ((y & ~(M)) >> Kk));       \
    }
    TSTEP(1, M1) TSTEP(2, M2) TSTEP(4, M4) TSTEP(8, M8) TSTEP(16, M16) TSTEP(32, M32)
#undef TSTEP
    A64[(base + dr * 64 + lane) * 16 + dc] = xv;
    return;
  }
  int mrow, col;
  if (NCOL == 2) {
    int xcd = bid & 7;               // pair (m, col0/1) shares bid mod 8
    int q = bid >> 3;
    col = q & 1;
    mrow = (xcd << 6) + (q >> 1);
  } else {
    mrow = bid;
    col = 0;
  }
  long row0 = (long)mrow * 128;
  int col0 = col * 128;
  int lane = threadIdx.x & 63, wave = threadIdx.x >> 6;
  int wi = (wave >> 1) * 64, wj = (wave & 1) * 64;
  int lr = lane & 15, lk = (lane >> 4) * 8;
  const __bf16* pAh = Ahi + (row0 + wi + lr) * (long)K + lk;
  const __bf16* pAl = Alo + (row0 + wi + lr) * (long)K + lk;
  const __bf16* pBh = Bhi + (long)(col0 + wj + lr) * K + lk;
  const __bf16* pBl = Blo + (long)(col0 + wj + lr) * K + lk;
  floatx4 zero = {0.f, 0.f, 0.f, 0.f};
  floatx4 acc[4][4];
#pragma unroll
  for (int i = 0; i < 4; ++i)
#pragma unroll
    for (int j = 0; j < 4; ++j) acc[i][j] = zero;
#pragma unroll
  for (int kk = 0; kk < (K >> 5); ++kk) {
    int k0 = kk * 32;
    bf16x8 ah[4], al[4], bh[4], bl[4];
#pragma unroll
    for (int t = 0; t < 4; ++t) {
      ah[t] = *(const bf16x8*)(pAh + (long)t * 16 * K + k0);
      al[t] = *(const bf16x8*)(pAl + (long)t * 16 * K + k0);
      bh[t] = *(const bf16x8*)(pBh + (long)t * 16 * K + k0);
      bl[t] = *(const bf16x8*)(pBl + (long)t * 16 * K + k0);
    }
#pragma unroll
    for (int tj = 0; tj < 4; ++tj)
#pragma unroll
      for (int ti = 0; ti < 4; ++ti) {
        acc[ti][tj] = MFMA_BF16(ah[ti], bh[tj], acc[ti][tj]);
        acc[ti][tj] = MFMA_BF16(ah[ti], bl[tj], acc[ti][tj]);
        acc[ti][tj] = MFMA_BF16(al[ti], bh[tj], acc[ti][tj]);
      }
  }
#pragma unroll
  for (int ti = 0; ti < 4; ++ti)
#pragma unroll
    for (int tj = 0; tj < 4; ++tj)
#pragma unroll
      for (int rr = 0; rr < 4; ++rr) {
        long grow = row0 + wi + ti * 16 + (lane >> 4) * 4 + rr;
        int gcol = col0 + wj + tj * 16 + (lane & 15);
        C[grow * ldc + gcol] = acc[ti][tj][rr];
      }
}

// ---------------------------------------------------------------------------
// K3: sage1, float4 form (R12).  8 nodes per 256-thread block; 32 lanes per
// node, each lane owns 4 consecutive h (float4 loads of YR1).
__global__ __launch_bounds__(256) void sage1_kernel(
    const unsigned int* __restrict__ Abits32, const float* __restrict__ YR1,
    const float* __restrict__ b1l, const float* __restrict__ Wrel,
    const float* __restrict__ Wroot, float* __restrict__ x1,
    float* __restrict__ p1, float* __restrict__ q1) {
  int g = threadIdx.x >> 5;          // 8 node-groups of 32 lanes
  int lane = threadIdx.x & 31;
  int node = blockIdx.x * 8 + g;     // b*1024+n
  int b = node >> 10, nloc = node & 1023;
  __shared__ int list[8][1024];
  __shared__ int s_deg[8];
  {
    unsigned int word = Abits32[(long)node * 32 + lane];
    int cnt = __popc(word);
    int off = cnt;
#pragma unroll
    for (int o = 1; o < 32; o <<= 1) {
      int v = __shfl_up(off, o, 32);
      if (lane >= o) off += v;
    }
    off -= cnt;  // exclusive prefix (ascending word order -> ordered list)
    if (lane == 31) s_deg[g] = off + cnt;
    int basei = lane * 32;
    while (word) {
      int t = __ffs(word) - 1;
      word &= word - 1;
      list[g][off++] = basei + t;
    }
  }
  __syncthreads();
  int deg = s_deg[g];
  const float4* Y4 = (const float4*)(YR1 + (long)(b << 10) * 256);  // 64 f4/row
  float4 a4 = {0.f, 0.f, 0.f, 0.f};
  for (int d = 0; d < deg; ++d) {
    float4 y = Y4[(long)list[g][d] * 64 + lane];
    a4.x += y.x; a4.y += y.y; a4.z += y.z; a4.w += y.w;
  }
  float4 R = Y4[(long)nloc * 64 + 32 + lane];
  float inv = 1.f / (float)(deg < 1 ? 1 : deg);
  float4 bl = ((const float4*)b1l)[lane];
  float4 v;
  v.x = fmaxf(a4.x * inv + bl.x + R.x, 0.f);
  v.y = fmaxf(a4.y * inv + bl.y + R.y, 0.f);
  v.z = fmaxf(a4.z * inv + bl.z + R.z, 0.f);
  v.w = fmaxf(a4.w * inv + bl.w + R.w, 0.f);
  ((float4*)x1)[(long)node * 32 + lane] = v;
  float4 wr = ((const float4*)Wrel)[lane];
  float4 wq = ((const float4*)Wroot)[lane];
  float pv = v.x * wr.x + v.y * wr.y + v.z * wr.z + v.w * wr.w;
  float qv = v.x * wq.x + v.y * wq.y + v.z * wq.z + v.w * wq.w;
#pragma unroll
  for (int o = 16; o; o >>= 1) {
    pv += __shfl_xor(pv, o, 32);
    qv += __shfl_xor(qv, o, 32);
  }
  if (lane == 0) { p1[node] = pv; q1[node] = qv; }
}

// ---------------------------------------------------------------------------
// K4+K5 fused: per-batch score (thread-per-row) + radix top-k selection.
__global__ void scoretopk_kernel(const unsigned int* __restrict__ bits32,
                                 const float* __restrict__ p,
                                 const float* __restrict__ q,
                                 const float* __restrict__ brel,
                                 int* __restrict__ idx_out,
                                 float* __restrict__ gate_out,
                                 int nwords, int rpb_shift, int k) {
  int b = blockIdx.x, tid = threadIdx.x;
  int row = (b << rpb_shift) + tid;
  const unsigned int* wptr = bits32 + (long)row * nwords;
  const float* pb = p + ((long)b << rpb_shift);
  float s = q[row] + brel[0];
  for (int w = 0; w < nwords; ++w) {
    unsigned int word = wptr[w];
    while (word) {
      int t = __ffs(word) - 1;
      word &= word - 1;
      s += pb[w * 32 + t];
    }
  }
  unsigned int fb = __float_as_uint(s);
  unsigned int key = (fb & 0x80000000u) ? ~fb : (fb | 0x80000000u);
  __shared__ int hist[256];
  __shared__ unsigned int sh_prefix;
  __shared__ int sh_target, cnt_gt, cnt_eq, outpos;
  if (tid == 0) { sh_prefix = 0; sh_target = k; cnt_gt = 0; cnt_eq = 0; outpos = 0; }
  for (int shift = 24; shift >= 0; shift -= 8) {
    if (tid < 256) hist[tid] = 0;
    __syncthreads();
    unsigned int prefix = sh_prefix;
    bool inset = (shift == 24) || ((key >> (shift + 8)) == (prefix >> (shift + 8)));
    if (inset) atomicAdd(&hist[(key >> shift) & 255], 1);
    __syncthreads();
    if (tid < 64) {
      int lane = tid;
      int bb0 = hist[255 - 4 * lane];
      int bb1 = hist[254 - 4 * lane];
      int bb2 = hist[253 - 4 * lane];
      int bb3 = hist[252 - 4 * lane];
      int c0 = bb0, c1 = c0 + bb1, c2 = c1 + bb2, c3 = c2 + bb3;
      int incl = c3;
#pragma unroll
      for (int o = 1; o < 64; o <<= 1) {
        int v = __shfl_up(incl, o);
        if (lane >= o) incl += v;
      }
      int excl = incl - c3;
      int target = sh_target;  // read before any lane writes (lockstep)
      int cum[4] = {excl + c0, excl + c1, excl + c2, excl + c3};
      int prev = excl;
#pragma unroll
      for (int i = 0; i < 4; ++i) {
        if (cum[i] >= target && prev < target) {
          int bin = 255 - (4 * lane + i);
          sh_prefix = prefix | ((unsigned int)bin << shift);
          sh_target = target - prev;
        }
        prev = cum[i];
      }
    }
    __syncthreads();
  }
  unsigned int T = sh_prefix;
  if (key > T) atomicAdd(&cnt_gt, 1);
  __syncthreads();
  int E = k - cnt_gt;
  bool sel = (key > T);
  if (!sel && key == T) sel = (atomicAdd(&cnt_eq, 1) < E);
  if (sel) {
    int posn = atomicAdd(&outpos, 1);
    idx_out[b * k + posn] = tid;
    gate_out[b * k + posn] = tanhf(s);
  }
}

// K6: fused gather: x1 rows * tanh gate -> split bf16, and A1 bit gather.
__global__ __launch_bounds__(256) void gather_kernel(
    const float* __restrict__ x1, const int* __restrict__ idx,
    const float* __restrict__ gate, __bf16* __restrict__ ghi,
    __bf16* __restrict__ glo, const unsigned int* __restrict__ Abits32,
    unsigned long long* __restrict__ A1bits) {
  int bid = blockIdx.x;
  if (bid < 16384) {
    long e = (long)bid * 256 + threadIdx.x;  // B*512*128
    int h = (int)(e & 127);
    int i = (int)((e >> 7) & 511);
    int b = (int)(e >> 16);
    int srow = idx[(b << 9) + i];
    float v = x1[((long)(b << 10) + srow) * 128 + h] * gate[(b << 9) + i];
    __bf16 a = (__bf16)v;
    ghi[e] = a;
    glo[e] = (__bf16)(v - (float)a);
  } else {
    int gi = (bid - 16384) * 4 + (threadIdx.x >> 6);  // b*512+i
    int lane = threadIdx.x & 63;
    int b = gi >> 9;
    int srow = idx[gi];
    const unsigned int* src = Abits32 + ((long)(b << 10) + srow) * 32;
    const int* idxb = idx + (b << 9);
#pragma unroll
    for (int t = 0; t < 8; ++t) {
      int cj = idxb[t * 64 + lane];
      int bit = (src[cj >> 5] >> (cj & 31)) & 1;
      unsigned long long m = __ballot(bit);
      if (lane == 0) A1bits[(long)gi * 8 + t] = m;
    }
  }
}

// K8: sage2, float4 form (R12).  16 nodes per 256-thread block; 16 lanes per
// node, each lane owns 4 consecutive h.
__global__ __launch_bounds__(256) void sage2_kernel(
    const unsigned int* __restrict__ A1b32, const float* __restrict__ YR2,
    const float* __restrict__ b2l, const float* __restrict__ Wrel,
    const float* __restrict__ Wroot, float* __restrict__ x2,
    float* __restrict__ p2, float* __restrict__ q2) {
  int g = threadIdx.x >> 4;          // 16 node-groups of 16 lanes
  int lane = threadIdx.x & 15;
  int row = blockIdx.x * 16 + g;     // b*512+i
  int b = row >> 9, iloc = row & 511;
  __shared__ int list[16][512];
  __shared__ int s_deg[16];
  {
    unsigned int word = A1b32[(long)row * 16 + lane];
    int cnt = __popc(word);
    int off = cnt;
#pragma unroll
    for (int o = 1; o < 16; o <<= 1) {
      int v = __shfl_up(off, o, 16);
      if (lane >= o) off += v;
    }
    off -= cnt;
    if (lane == 15) s_deg[g] = off + cnt;
    int basei = lane * 32;
    while (word) {
      int t = __ffs(word) - 1;
      word &= word - 1;
      list[g][off++] = basei + t;
    }
  }
  __syncthreads();
  int deg = s_deg[g];
  const float4* Y4 = (const float4*)(YR2 + (long)(b << 9) * 128);  // 32 f4/row
  float4 a4 = {0.f, 0.f, 0.f, 0.f};
  for (int d = 0; d < deg; ++d) {
    float4 y = Y4[(long)list[g][d] * 32 + lane];
    a4.x += y.x; a4.y += y.y; a4.z += y.z; a4.w += y.w;
  }
  float4 R = Y4[(long)iloc * 32 + 16 + lane];
  float inv = 1.f / (float)(deg < 1 ? 1 : deg);
  float4 bl = ((const float4*)b2l)[lane];
  float4 v;
  v.x = fmaxf(a4.x * inv + bl.x + R.x, 0.f);
  v.y = fmaxf(a4.y * inv + bl.y + R.y, 0.f);
  v.z = fmaxf(a4.z * inv + bl.z + R.z, 0.f);
  v.w = fmaxf(a4.w * inv + bl.w + R.w, 0.f);
  ((float4*)x2)[(long)row * 16 + lane] = v;
  float4 wr = ((const float4*)Wrel)[lane];
  float4 wq = ((const float4*)Wroot)[lane];
  float pv = v.x * wr.x + v.y * wr.y + v.z * wr.z + v.w * wr.w;
  float qv = v.x * wq.x + v.y * wq.y + v.z * wq.z + v.w * wq.w;
#pragma unroll
  for (int o = 8; o; o >>= 1) {
    pv += __shfl_xor(pv, o, 16);
    qv += __shfl_xor(qv, o, 16);
  }
  if (lane == 0) { p2[row] = pv; q2[row] = qv; }
}

// ---------------------------------------------------------------------------
// K9+K10+K11 fused: per-batch score2 + topk2 (idx/gate in LDS) + MLP head.
__global__ __launch_bounds__(512) void scoretopk_head_kernel(
    const unsigned int* __restrict__ A1b32, const float* __restrict__ p2,
    const float* __restrict__ q2, const float* __restrict__ brel,
    const float* __restrict__ x2, const float* __restrict__ fc1_w,
    const float* __restrict__ fc1_b, const float* __restrict__ g1,
    const float* __restrict__ bb1, const float* __restrict__ m1,
    const float* __restrict__ v1, const float* __restrict__ fc2_w,
    const float* __restrict__ fc2_b, const float* __restrict__ g2,
    const float* __restrict__ bb2, const float* __restrict__ m2,
    const float* __restrict__ v2, const float* __restrict__ fc3_w,
    const float* __restrict__ fc3_b, float* __restrict__ out) {
  int b = blockIdx.x, tid = threadIdx.x;
  // ---- score (thread-per-row, 512 rows, 16 words) ----
  int row = (b << 9) + tid;
  const unsigned int* wptr = A1b32 + (long)row * 16;
  const float* pb = p2 + ((long)b << 9);
  float s = q2[row] + brel[0];
  for (int w = 0; w < 16; ++w) {
    unsigned int word = wptr[w];
    while (word) {
      int t = __ffs(word) - 1;
      word &= word - 1;
      s += pb[w * 32 + t];
    }
  }
  // ---- top-256 radix select into LDS ----
  constexpr int k = KP2;
  unsigned int fb = __float_as_uint(s);
  unsigned int key = (fb & 0x80000000u) ? ~fb : (fb | 0x80000000u);
  __shared__ int hist[256];
  __shared__ int idx2s[256];
  __shared__ float gate2s[256];
  __shared__ unsigned int sh_prefix;
  __shared__ int sh_target, cnt_gt, cnt_eq, outpos;
  if (tid == 0) { sh_prefix = 0; sh_target = k; cnt_gt = 0; cnt_eq = 0; outpos = 0; }
  for (int shift = 24; shift >= 0; shift -= 8) {
    if (tid < 256) hist[tid] = 0;
    __syncthreads();
    unsigned int prefix = sh_prefix;
    bool inset = (shift == 24) || ((key >> (shift + 8)) == (prefix >> (shift + 8)));
    if (inset) atomicAdd(&hist[(key >> shift) & 255], 1);
    __syncthreads();
    if (tid < 64) {
      int lane = tid;
      int bb0 = hist[255 - 4 * lane];
      int bb1 = hist[254 - 4 * lane];
      int bb2 = hist[253 - 4 * lane];
      int bb3 = hist[252 - 4 * lane];
      int c0 = bb0, c1 = c0 + bb1, c2 = c1 + bb2, c3 = c2 + bb3;
      int incl = c3;
#pragma unroll
      for (int o = 1; o < 64; o <<= 1) {
        int v = __shfl_up(incl, o);
        if (lane >= o) incl += v;
      }
      int excl = incl - c3;
      int target = sh_target;
      int cum[4] = {excl + c0, excl + c1, excl + c2, excl + c3};
      int prev = excl;
#pragma unroll
      for (int i = 0; i < 4; ++i) {
        if (cum[i] >= target && prev < target) {
          int bin = 255 - (4 * lane + i);
          sh_prefix = prefix | ((unsigned int)bin << shift);
          sh_target = target - prev;
        }
        prev = cum[i];
      }
    }
    __syncthreads();
  }
  unsigned int T = sh_prefix;
  if (key > T) atomicAdd(&cnt_gt, 1);
  __syncthreads();
  int E = k - cnt_gt;
  bool sel = (key > T);
  if (!sel && key == T) sel = (atomicAdd(&cnt_eq, 1) < E);
  if (sel) {
    int posn = atomicAdd(&outpos, 1);
    idx2s[posn] = tid;
    gate2s[posn] = tanhf(s);
  }
  __syncthreads();
  // ---- head: mean pool over selected + MLP + softmax ----
  __shared__ float part[8][64];
  __shared__ float pooled[64];
  __shared__ float h1[512];
  __shared__ float h2[256];
  __shared__ float zz[2];
  int h = tid & 63, grp = tid >> 6;
  float sp = 0.f;
  for (int i = grp * 32; i < grp * 32 + 32; ++i) {
    int si = idx2s[i];
    sp += x2[((long)(b << 9) + si) * 64 + h] * gate2s[i];
  }
  part[grp][h] = sp;
  __syncthreads();
  if (tid < 64) {
    float t = 0.f;
#pragma unroll
    for (int g = 0; g < 8; ++g) t += part[g][tid];
    pooled[tid] = t * (1.f / 256.f);
  }
  __syncthreads();
  {
    float z = fc1_b[tid];
    for (int j = 0; j < 64; ++j) z += pooled[j] * fc1_w[tid * 64 + j];
    z = fmaxf(z, 0.f);
    h1[tid] = g1[tid] * (z - m1[tid]) * rsqrtf(v1[tid] + 1e-5f) + bb1[tid];
  }
  __syncthreads();
  if (tid < 256) {
    float z = fc2_b[tid];
    for (int j = 0; j < 512; ++j) z += h1[j] * fc2_w[tid * 512 + j];
    z = fmaxf(z, 0.f);
    h2[tid] = g2[tid] * (z - m2[tid]) * rsqrtf(v2[tid] + 1e-5f) + bb2[tid];
  }
  __syncthreads();
  if (tid < 2) {
    float z = fc3_b[tid];
    for (int j = 0; j < 256; ++j) z += h2[j] * fc3_w[tid * 256 + j];
    zz[tid] = z;
  }
  __syncthreads();
  if (tid == 0) {
    float mx = fmaxf(zz[0], zz[1]);
    float e0 = expf(zz[0] - mx), e1 = expf(zz[1] - mx);
    float inv = 1.f / (e0 + e1);
    out[b * 2 + 0] = e0 * inv;
    out[b * 2 + 1] = e1 * inv;
  }
}

// ---------------------------------------------------------------------------
extern "C" void kernel_launch(void* const* d_in, const int* in_sizes, int n_in,
                              void* d_out, int out_size, void* d_ws, size_t ws_size,
                              hipStream_t stream) {
  (void)in_sizes; (void)n_in; (void)out_size; (void)ws_size;
  const float* input   = (const float*)d_in[0];
  const float* W1l     = (const float*)d_in[1];
  const float* b1l     = (const float*)d_in[2];
  const float* W1r     = (const float*)d_in[3];
  const float* Wp1_rel = (const float*)d_in[4];
  const float* bp1_rel = (const float*)d_in[5];
  const float* Wp1_root= (const float*)d_in[6];
  const float* W2l     = (const float*)d_in[7];
  const float* b2l     = (const float*)d_in[8];
  const float* W2r     = (const float*)d_in[9];
  const float* Wp2_rel = (const float*)d_in[10];
  const float* bp2_rel = (const float*)d_in[11];
  const float* Wp2_root= (const float*)d_in[12];
  const float* fc1_w   = (const float*)d_in[13];
  const float* fc1_b   = (const float*)d_in[14];
  const float* bn1_g   = (const float*)d_in[15];
  const float* bn1_b   = (const float*)d_in[16];
  const float* bn1_m   = (const float*)d_in[17];
  const float* bn1_v   = (const float*)d_in[18];
  const float* fc2_w   = (const float*)d_in[19];
  const float* fc2_b   = (const float*)d_in[20];
  const float* bn2_g   = (const float*)d_in[21];
  const float* bn2_b   = (const float*)d_in[22];
  const float* bn2_m   = (const float*)d_in[23];
  const float* bn2_v   = (const float*)d_in[24];
  const float* fc3_w   = (const float*)d_in[25];
  const float* fc3_b   = (const float*)d_in[26];

  char* ws = (char*)d_ws;
  __bf16* xhi   = (__bf16*)(ws + OFF_XHI);
  __bf16* xlo   = (__bf16*)(ws + OFF_XLO);
  unsigned char* xhat8 = (unsigned char*)(ws + OFF_XHAT);
  unsigned short* Abits = (unsigned short*)(ws + OFF_ABITS);
  const unsigned int* Abits32 = (const unsigned int*)(ws + OFF_ABITS);
  unsigned long long* A64 = (unsigned long long*)(ws + OFF_ABITS);
  float* YR1    = (float*)(ws + OFF_YR1);
  float* x1     = (float*)(ws + OFF_X1);
  float* p1     = (float*)(ws + OFF_P1);
  float* q1     = (float*)(ws + OFF_Q1);
  int*   idx1   = (int*)(ws + OFF_IDX1);
  float* gate1  = (float*)(ws + OFF_GATE1);
  float* p2     = (float*)(ws + OFF_P2);
  float* q2     = (float*)(ws + OFF_Q2);
  __bf16* w1hi  = (__bf16*)(ws + OFF_W1HI);
  __bf16* w1lo  = (__bf16*)(ws + OFF_W1LO);
  __bf16* w2hi  = (__bf16*)(ws + OFF_W2HI);
  __bf16* w2lo  = (__bf16*)(ws + OFF_W2LO);
  __bf16* ghi   = (__bf16*)(ws + OFF_GHI);
  __bf16* glo   = (__bf16*)(ws + OFF_GLO);
  unsigned long long* A1bits = (unsigned long long*)(ws + OFF_A1B);
  const unsigned int* A1b32  = (const unsigned int*)(ws + OFF_A1B);
  float* YR2    = (float*)(ws + OFF_YR2);
  float* x2     = (float*)(ws + OFF_X2);
  float* out    = (float*)d_out;

  prep_pack_kernel<<<16672, 256, 0, stream>>>(input, xhi, xlo, xhat8,
                                              W1l, W1r, w1hi, w1lo,
                                              W2l, W2r, w2hi, w2lo);
  corr_kernel<<<2304, 256, 0, stream>>>(xhat8, Abits);
  // gemm1: 512 M-blocks x 2 N-blocks (XCD-paired) + 1792 transpose blocks
  gemm_split_kernel<224, 2><<<1024 + 1792, 256, 0, stream>>>(
      xhi, xlo, w1hi, w1lo, YR1, 512, A64, 1792);
  sage1_kernel<<<8192, 256, 0, stream>>>(Abits32, YR1, b1l, Wp1_rel, Wp1_root, x1, p1, q1);
  scoretopk_kernel<<<64, 1024, 0, stream>>>(Abits32, p1, q1, bp1_rel, idx1, gate1,
                                            32, 10, KP1);
  gather_kernel<<<24576, 256, 0, stream>>>(x1, idx1, gate1, ghi, glo, Abits32, A1bits);
  gemm_split_kernel<128, 1><<<256, 256, 0, stream>>>(
      ghi, glo, w2hi, w2lo, YR2, 256, nullptr, 0);
  sage2_kernel<<<2048, 256, 0, stream>>>(A1b32, YR2, b2l, Wp2_rel, Wp2_root, x2, p2, q2);
  scoretopk_head_kernel<<<64, 512, 0, stream>>>(A1b32, p2, q2, bp2_rel, x2,
                                                fc1_w, fc1_b, bn1_g, bn1_b, bn1_m, bn1_v,
                                                fc2_w, fc2_b, bn2_g, bn2_b, bn2_m, bn2_v,
                                                fc3_w, fc3_b, out);
}